// Round 10
// baseline (587.263 us; speedup 1.0000x reference)
//
#include <hip/hip_runtime.h>

#define G 300
#define PIX (G*G)
#define CD 16
#define NS 512
#define STEP_F 0.005016722408026756f
#define C23 (2.0f/3.0f)

__device__ __forceinline__ float softplus_stable(float x){
    return (x > 0.f) ? (x + log1pf(expf(-x))) : log1pf(expf(x));
}

// Contraction barrier: pins x to a VGPR and "observes" it, so mul->add pairs
// across it CANNOT be fused into FMA. (HIP's __fmul_rn/__fadd_rn are NOT
// barriers — R2/R3 benches were bit-identical with/without them.)
__device__ __forceinline__ float nofuse(float x){
    asm("" : "+v"(x));
    return x;
}

// ---------------- transpose: [3][16][H][W] -> [3][H][W][16] ----------------
__global__ void k_tr_plane(const float* __restrict__ in, float* __restrict__ out){
    int pix = blockIdx.x * blockDim.x + threadIdx.x;
    if (pix >= 3*PIX) return;
    int p = pix / PIX;
    int rem = pix - p*PIX;
    float v[CD];
    #pragma unroll
    for (int c = 0; c < CD; ++c) v[c] = in[((size_t)(p*CD + c))*PIX + rem];
    float4* o4 = (float4*)(out + (size_t)pix*CD);
    #pragma unroll
    for (int q = 0; q < 4; ++q) o4[q] = make_float4(v[4*q+0], v[4*q+1], v[4*q+2], v[4*q+3]);
}

__global__ void k_tr_line(const float* __restrict__ in, float* __restrict__ out){
    int i = blockIdx.x * blockDim.x + threadIdx.x;
    if (i >= 3*G) return;
    int p = i / G;
    int z = i - p*G;
    float v[CD];
    #pragma unroll
    for (int c = 0; c < CD; ++c) v[c] = in[((size_t)(p*CD + c))*G + z];
    float4* o4 = (float4*)(out + (size_t)i*CD);
    #pragma unroll
    for (int q = 0; q < 4; ++q) o4[q] = make_float4(v[4*q+0], v[4*q+1], v[4*q+2], v[4*q+3]);
}

// f32 tmin chain: subs/divs/min/max only — no contractible mul+add pairs.
__device__ __forceinline__ float ray_tmin_f(float ox, float oy, float oz,
                                            float dx, float dy, float dz){
    const float vx = (dx == 0.f) ? 1e-6f : dx;
    const float vy = (dy == 0.f) ? 1e-6f : dy;
    const float vz = (dz == 0.f) ? 1e-6f : dz;
    const float ax = (1.5f - ox) / vx;
    const float bx = (-1.5f - ox) / vx;
    const float ay = (1.5f - oy) / vy;
    const float by = (-1.5f - oy) / vy;
    const float az = (1.5f - oz) / vz;
    const float bz = (-1.5f - oz) / vz;
    float t = fmaxf(fmaxf(fminf(ax,bx), fminf(ay,by)), fminf(az,bz));
    return fminf(fmaxf(t, 2.0f), 6.0f);
}

// ------- density: unfused-f32 decisions + float4 transposed taps + f64 parallel scan -------
__global__ __launch_bounds__(512) void k_density(
    const float* __restrict__ rays,
    const float* __restrict__ tp, const float* __restrict__ tl,
    float* __restrict__ acc_out, float* __restrict__ depth_out,
    int* __restrict__ cnt, int* __restrict__ cidx, float* __restrict__ cw)
{
    __shared__ double s_wprod[8];
    __shared__ double s_acc[8];
    __shared__ double s_dep[8];
    __shared__ int    s_wbase[8];
    __shared__ int    s_gbase;

    const int r    = blockIdx.x;
    const int s    = threadIdx.x;
    const int lane = s & 63;
    const int wid  = s >> 6;

    const float oxf = rays[r*6+0], oyf = rays[r*6+1], ozf = rays[r*6+2];
    const float dxf = rays[r*6+3], dyf = rays[r*6+4], dzf = rays[r*6+5];

    const float tmin = ray_tmin_f(oxf, oyf, ozf, dxf, dyf, dzf);

    // numpy-exact UNFUSED: z = tmin + (STEP*s); p = o + (d*z)
    const float zv   = tmin + nofuse(STEP_F * (float)s);
    const float zv1  = tmin + nofuse(STEP_F * (float)(s+1));
    const float dist = (s == NS-1) ? 0.f : (zv1 - zv);

    const float px = oxf + nofuse(dxf * zv);
    const float py = oyf + nofuse(dyf * zv);
    const float pz = ozf + nofuse(dzf * zv);
    const bool valid = (px >= -1.5f) && (px <= 1.5f) && (py >= -1.5f) && (py <= 1.5f)
                    && (pz >= -1.5f) && (pz <= 1.5f);

    float alpha = 0.f;
    if (valid){
        // xyz_n = (p+1.5)*C23 - 1 : unfused mul then sub
        const float xn = nofuse((px + 1.5f)*C23) - 1.f;
        const float yn = nofuse((py + 1.5f)*C23) - 1.f;
        const float zn = nofuse((pz + 1.5f)*C23) - 1.f;
        const float pu[3] = {xn, xn, yn};
        const float pv[3] = {yn, zn, zn};
        const float pl[3] = {zn, yn, xn};
        float feat = 0.f;
        #pragma unroll
        for (int pp = 0; pp < 3; ++pp){
            const float fx = (pu[pp] + 1.f) * 0.5f * (float)(G-1);
            const float fy = (pv[pp] + 1.f) * 0.5f * (float)(G-1);
            const float fz = (pl[pp] + 1.f) * 0.5f * (float)(G-1);
            const float x0f = floorf(fx), y0f = floorf(fy), z0f = floorf(fz);
            const float wx = fx - x0f, wy = fy - y0f, wz = fz - z0f;
            const int x0 = (int)x0f, y0 = (int)y0f, zq0 = (int)z0f;
            const int x1 = min(x0+1, G-1), y1 = min(y0+1, G-1), zq1 = min(zq0+1, G-1);
            const float wxe = (x0  + 1 < G) ? wx : 0.f;
            const float wye = (y0  + 1 < G) ? wy : 0.f;
            const float wze = (zq0 + 1 < G) ? wz : 0.f;
            const float w00 = (1.f-wx)*(1.f-wy);
            const float w01 = wxe*(1.f-wy);
            const float w10 = (1.f-wx)*wye;
            const float w11 = wxe*wye;
            const float u0 = 1.f - wz, u1 = wze;
            const float4* b00 = (const float4*)(tp + ((size_t)pp*PIX + y0*G + x0)*CD);
            const float4* b01 = (const float4*)(tp + ((size_t)pp*PIX + y0*G + x1)*CD);
            const float4* b10 = (const float4*)(tp + ((size_t)pp*PIX + y1*G + x0)*CD);
            const float4* b11 = (const float4*)(tp + ((size_t)pp*PIX + y1*G + x1)*CD);
            const float4* l0  = (const float4*)(tl + ((size_t)pp*G + zq0)*CD);
            const float4* l1  = (const float4*)(tl + ((size_t)pp*G + zq1)*CD);
            #pragma unroll
            for (int q = 0; q < 4; ++q){
                const float4 t00 = b00[q], t01 = b01[q], t10 = b10[q], t11 = b11[q];
                const float4 a0 = l0[q], a1 = l1[q];
                feat += (w00*t00.x + w01*t01.x + w10*t10.x + w11*t11.x) * (u0*a0.x + u1*a1.x);
                feat += (w00*t00.y + w01*t01.y + w10*t10.y + w11*t11.y) * (u0*a0.y + u1*a1.y);
                feat += (w00*t00.z + w01*t01.z + w10*t10.z + w11*t11.z) * (u0*a0.z + u1*a1.z);
                feat += (w00*t00.w + w01*t01.w + w10*t10.w + w11*t11.w) * (u0*a0.w + u1*a1.w);
            }
        }
        const float sigma = softplus_stable(feat - 10.0f);
        alpha = 1.f - expf(-(sigma * dist * 25.0f));
    }

    // f64 transmittance scan (order-robust; continuous effect only)
    const double term = (1.0 - (double)alpha) + 1e-10;
    double v = term;
    #pragma unroll
    for (int off = 1; off < 64; off <<= 1){
        double u = __shfl_up(v, off, 64);
        if (lane >= off) v *= u;
    }
    double excl = __shfl_up(v, 1, 64);
    if (lane == 0) excl = 1.0;
    if (lane == 63) s_wprod[wid] = v;
    __syncthreads();
    if (s == 0){
        double p = 1.0;
        #pragma unroll
        for (int w = 0; w < 8; ++w){ double t = s_wprod[w]; s_wprod[w] = p; p *= t; }
    }
    __syncthreads();
    const double T = excl * s_wprod[wid];
    const double w = (double)alpha * T;

    double a_c = w;
    double d_c = w * (double)zv;
    #pragma unroll
    for (int off = 32; off > 0; off >>= 1){
        a_c += __shfl_down(a_c, off, 64);
        d_c += __shfl_down(d_c, off, 64);
    }
    if (lane == 0){ s_acc[wid] = a_c; s_dep[wid] = d_c; }

    const bool keep = w > 1e-4;
    const unsigned long long m = __ballot(keep);
    if (lane == 0) s_wbase[wid] = __popcll(m);
    __syncthreads();
    if (s == 0){
        double A = 0.0, D = 0.0;
        #pragma unroll
        for (int q = 0; q < 8; ++q){ A += s_acc[q]; D += s_dep[q]; }
        acc_out[r] = (float)A; depth_out[r] = (float)D;
        int tot = 0;
        #pragma unroll
        for (int q = 0; q < 8; ++q){ int c = s_wbase[q]; s_wbase[q] = tot; tot += c; }
        s_gbase = atomicAdd(cnt, tot);
    }
    __syncthreads();
    if (keep){
        const int off = s_gbase + s_wbase[wid] + (int)__popcll(m & ((1ull << lane) - 1ull));
        cidx[off] = (r << 9) | s;
        cw[off]   = (float)w;
    }
}

// ------------- color sampling + MLP on compacted points -------------
__global__ __launch_bounds__(256) void k_color(
    const float* __restrict__ rays,
    const float* __restrict__ tp, const float* __restrict__ tl,
    const float* __restrict__ bw,
    const float* __restrict__ w1, const float* __restrict__ b1,
    const float* __restrict__ w2, const float* __restrict__ b2,
    const float* __restrict__ w3, const float* __restrict__ b3,
    const int* __restrict__ cnt, const int* __restrict__ cidx, const float* __restrict__ cw,
    float* __restrict__ rgb_sum)
{
    __shared__ float X [150][32];
    __shared__ float H1[128][32];
    __shared__ float H2[128][32];
    __shared__ float xn_s[3][32];
    __shared__ int   pid[32];
    __shared__ float pw [32];
    float (*F)[32] = (float(*)[32])H1;   // F[48][32] aliases H1 (dead before H1 written)

    const int t = threadIdx.x;
    const int p = t & 31;
    const int g = t >> 5;
    const int count   = *cnt;
    const int nchunks = (count + 31) >> 5;

    for (int ch = blockIdx.x; ch < nchunks; ch += gridDim.x){
        const int base = ch << 5;

        if (t < 32){
            const int i  = base + t;
            const int id = (i < count) ? cidx[i] : -1;
            pid[t] = id;
            pw[t]  = (i < count) ? cw[i] : 0.f;
            float xn = 0.f, yn = 0.f, zn = 0.f, ddx = 0.f, ddy = 0.f, ddz = 0.f;
            if (id >= 0){
                const int r = id >> 9, sm = id & 511;
                const float oxf = rays[r*6+0], oyf = rays[r*6+1], ozf = rays[r*6+2];
                ddx = rays[r*6+3]; ddy = rays[r*6+4]; ddz = rays[r*6+5];
                const float tmin = ray_tmin_f(oxf, oyf, ozf, ddx, ddy, ddz);
                const float zv = tmin + nofuse(STEP_F * (float)sm);
                const float px = oxf + nofuse(ddx * zv);
                const float py = oyf + nofuse(ddy * zv);
                const float pz = ozf + nofuse(ddz * zv);
                xn = nofuse((px + 1.5f)*C23) - 1.f;
                yn = nofuse((py + 1.5f)*C23) - 1.f;
                zn = nofuse((pz + 1.5f)*C23) - 1.f;
            }
            xn_s[0][t] = xn; xn_s[1][t] = yn; xn_s[2][t] = zn;
            X[27][t] = ddx; X[28][t] = ddy; X[29][t] = ddz;
        }
        __syncthreads();

        {
            const int c0 = g*2;
            const bool live = pid[p] >= 0;
            const float xn = xn_s[0][p], yn = xn_s[1][p], zn = xn_s[2][p];
            const float pu[3] = {xn, xn, yn};
            const float pv[3] = {yn, zn, zn};
            const float pl[3] = {zn, yn, xn};
            #pragma unroll
            for (int pp = 0; pp < 3; ++pp){
                float f0 = 0.f, f1 = 0.f;
                if (live){
                    const float fx = (pu[pp] + 1.f) * 0.5f * (float)(G-1);
                    const float fy = (pv[pp] + 1.f) * 0.5f * (float)(G-1);
                    const float fz = (pl[pp] + 1.f) * 0.5f * (float)(G-1);
                    const float x0f = floorf(fx), y0f = floorf(fy), z0f = floorf(fz);
                    const float wx = fx - x0f, wy = fy - y0f, wz = fz - z0f;
                    const int x0 = (int)x0f, y0 = (int)y0f, zq0 = (int)z0f;
                    const int x1 = min(x0+1, G-1), y1 = min(y0+1, G-1), zq1 = min(zq0+1, G-1);
                    const float wxe = (x0  < G-1) ? wx : 0.f;
                    const float wye = (y0  < G-1) ? wy : 0.f;
                    const float wze = (zq0 < G-1) ? wz : 0.f;
                    const float w00 = (1.f-wx)*(1.f-wy);
                    const float w01 = wxe*(1.f-wy);
                    const float w10 = (1.f-wx)*wye;
                    const float w11 = wxe*wye;
                    const float u0 = 1.f - wz, u1 = wze;
                    const float* base00 = tp + ((size_t)pp*PIX + y0*G + x0)*CD + c0;
                    const float* base01 = tp + ((size_t)pp*PIX + y0*G + x1)*CD + c0;
                    const float* base10 = tp + ((size_t)pp*PIX + y1*G + x0)*CD + c0;
                    const float* base11 = tp + ((size_t)pp*PIX + y1*G + x1)*CD + c0;
                    const float* lb0    = tl + ((size_t)pp*G + zq0)*CD + c0;
                    const float* lb1    = tl + ((size_t)pp*G + zq1)*CD + c0;
                    const float2 t00 = *(const float2*)base00;
                    const float2 t01 = *(const float2*)base01;
                    const float2 t10 = *(const float2*)base10;
                    const float2 t11 = *(const float2*)base11;
                    const float2 a0  = *(const float2*)lb0;
                    const float2 a1  = *(const float2*)lb1;
                    f0 = (w00*t00.x + w01*t01.x + w10*t10.x + w11*t11.x) * (u0*a0.x + u1*a1.x);
                    f1 = (w00*t00.y + w01*t01.y + w10*t10.y + w11*t11.y) * (u0*a0.y + u1*a1.y);
                }
                F[pp*16 + c0    ][p] = f0;
                F[pp*16 + c0 + 1][p] = f1;
            }
        }
        __syncthreads();

        {
            const int o0 = g, o1 = g + 8, o2 = g + 16;
            const int o3 = (g < 3) ? (g + 24) : 0;
            float a0 = 0.f, a1 = 0.f, a2 = 0.f, a3 = 0.f;
            for (int k = 0; k < 48; k += 4){
                const float x0 = F[k  ][p], x1 = F[k+1][p];
                const float x2 = F[k+2][p], x3 = F[k+3][p];
                const float4 v0 = *(const float4*)(bw + o0*48 + k);
                const float4 v1 = *(const float4*)(bw + o1*48 + k);
                const float4 v2 = *(const float4*)(bw + o2*48 + k);
                const float4 v3 = *(const float4*)(bw + o3*48 + k);
                a0 = fmaf(v0.x,x0,fmaf(v0.y,x1,fmaf(v0.z,x2,fmaf(v0.w,x3,a0))));
                a1 = fmaf(v1.x,x0,fmaf(v1.y,x1,fmaf(v1.z,x2,fmaf(v1.w,x3,a1))));
                a2 = fmaf(v2.x,x0,fmaf(v2.y,x1,fmaf(v2.z,x2,fmaf(v2.w,x3,a2))));
                a3 = fmaf(v3.x,x0,fmaf(v3.y,x1,fmaf(v3.z,x2,fmaf(v3.w,x3,a3))));
            }
            __syncthreads();
            X[o0][p] = a0; X[o1][p] = a1; X[o2][p] = a2;
            if (g < 3) X[g+24][p] = a3;
        }
        __syncthreads();

        #pragma unroll
        for (int i = 0; i < 7; ++i){
            const int mf = g + 8*i;
            if (mf < 54){
                const int m = mf >> 1, f = mf & 1;
                const float a = X[m][p] * (f ? 2.f : 1.f);
                float sv, cv; sincosf(a, &sv, &cv);
                X[30+mf][p] = sv; X[84+mf][p] = cv;
            }
        }
        if (g < 6){
            const int j = g >> 1, f = g & 1;
            const float a = X[27+j][p] * (f ? 2.f : 1.f);
            float sv, cv; sincosf(a, &sv, &cv);
            X[138+g][p] = sv; X[144+g][p] = cv;
        }
        __syncthreads();

        #pragma unroll
        for (int q = 0; q < 2; ++q){
            const int jb = g + 64*q;
            float a[8];
            #pragma unroll
            for (int u = 0; u < 8; ++u) a[u] = b1[jb + 8*u];
            for (int k = 0; k < 150; k += 2){
                const float x0 = X[k][p], x1 = X[k+1][p];
                #pragma unroll
                for (int u = 0; u < 8; ++u){
                    const float2 w = *(const float2*)(w1 + (jb + 8*u)*150 + k);
                    a[u] = fmaf(w.y, x1, fmaf(w.x, x0, a[u]));
                }
            }
            #pragma unroll
            for (int u = 0; u < 8; ++u) H1[jb + 8*u][p] = fmaxf(a[u], 0.f);
        }
        __syncthreads();

        #pragma unroll
        for (int q = 0; q < 2; ++q){
            const int jb = g + 64*q;
            float a[8];
            #pragma unroll
            for (int u = 0; u < 8; ++u) a[u] = b2[jb + 8*u];
            for (int k = 0; k < 128; k += 4){
                const float x0 = H1[k  ][p], x1 = H1[k+1][p];
                const float x2 = H1[k+2][p], x3 = H1[k+3][p];
                #pragma unroll
                for (int u = 0; u < 8; ++u){
                    const float4 w = *(const float4*)(w2 + (jb + 8*u)*128 + k);
                    a[u] = fmaf(w.w,x3,fmaf(w.z,x2,fmaf(w.y,x1,fmaf(w.x,x0,a[u]))));
                }
            }
            #pragma unroll
            for (int u = 0; u < 8; ++u) H2[jb + 8*u][p] = fmaxf(a[u], 0.f);
        }
        __syncthreads();

        if (t < 96){
            const int j = g;
            if (pid[p] >= 0){
                float acc = b3[j];
                for (int k = 0; k < 128; k += 4){
                    const float4 w = *(const float4*)(w3 + j*128 + k);
                    acc = fmaf(w.x, H2[k  ][p], acc);
                    acc = fmaf(w.y, H2[k+1][p], acc);
                    acc = fmaf(w.z, H2[k+2][p], acc);
                    acc = fmaf(w.w, H2[k+3][p], acc);
                }
                const float rgb = 1.f / (1.f + expf(-acc));
                atomicAdd(&rgb_sum[(pid[p] >> 9)*3 + j], pw[p]*rgb);
            }
        }
        __syncthreads();
    }
}

// ------------- finalize -------------
__global__ void k_final(const float* __restrict__ rgb_sum, const float* __restrict__ acc,
                        const float* __restrict__ depth, float* __restrict__ out, int R){
    const int i = blockIdx.x * blockDim.x + threadIdx.x;
    if (i < R*3){
        const int r = i / 3;
        const float v = rgb_sum[i] + (1.f - acc[r]);
        out[i] = fminf(fmaxf(v, 0.f), 1.f);
    } else if (i < R*4){
        const int r = i - R*3;
        out[R*3 + r] = depth[r];
    }
}

extern "C" void kernel_launch(void* const* d_in, const int* in_sizes, int n_in,
                              void* d_out, int out_size, void* d_ws, size_t ws_size,
                              hipStream_t stream)
{
    const float* rays        = (const float*)d_in[0];
    const float* dense_plane = (const float*)d_in[1];
    const float* dense_line  = (const float*)d_in[2];
    const float* color_plane = (const float*)d_in[3];
    const float* color_line  = (const float*)d_in[4];
    const float* bw          = (const float*)d_in[5];
    const float* w1          = (const float*)d_in[6];
    const float* b1          = (const float*)d_in[7];
    const float* w2          = (const float*)d_in[8];
    const float* b2          = (const float*)d_in[9];
    const float* w3          = (const float*)d_in[10];
    const float* b3          = (const float*)d_in[11];
    const int R = in_sizes[0] / 6;   // 2048

    char* ws = (char*)d_ws;
    const size_t OFF_RGB  = 0;
    const size_t OFF_CNT  = (size_t)R*3*sizeof(float);
    const size_t OFF_ACC  = OFF_CNT + 256;
    const size_t OFF_DEP  = OFF_ACC + (size_t)R*sizeof(float);
    const size_t OFF_CIDX = OFF_DEP + (size_t)R*sizeof(float);
    const size_t OFF_CW   = OFF_CIDX + (size_t)R*NS*sizeof(int);
    const size_t OFF_TD   = OFF_CW  + (size_t)R*NS*sizeof(float);
    const size_t OFF_TC   = OFF_TD  + (size_t)3*PIX*CD*sizeof(float);
    const size_t OFF_TDL  = OFF_TC  + (size_t)3*PIX*CD*sizeof(float);
    const size_t OFF_TCL  = OFF_TDL + (size_t)3*G*CD*sizeof(float);

    float* rgb_sum = (float*)(ws + OFF_RGB);
    int*   cnt     = (int*)  (ws + OFF_CNT);
    float* accb    = (float*)(ws + OFF_ACC);
    float* depthb  = (float*)(ws + OFF_DEP);
    int*   cidx    = (int*)  (ws + OFF_CIDX);
    float* cw      = (float*)(ws + OFF_CW);
    float* td      = (float*)(ws + OFF_TD);
    float* tc      = (float*)(ws + OFF_TC);
    float* tdl     = (float*)(ws + OFF_TDL);
    float* tcl     = (float*)(ws + OFF_TCL);

    hipMemsetAsync(ws, 0, OFF_CNT + sizeof(int), stream);

    const int pixb = (3*PIX + 255)/256;
    k_tr_plane<<<pixb, 256, 0, stream>>>(dense_plane, td);
    k_tr_plane<<<pixb, 256, 0, stream>>>(color_plane, tc);
    const int linb = (3*G + 255)/256;
    k_tr_line<<<linb, 256, 0, stream>>>(dense_line, tdl);
    k_tr_line<<<linb, 256, 0, stream>>>(color_line, tcl);

    k_density<<<R, 512, 0, stream>>>(rays, td, tdl, accb, depthb, cnt, cidx, cw);
    k_color<<<768, 256, 0, stream>>>(rays, tc, tcl, bw, w1, b1, w2, b2, w3, b3,
                                     cnt, cidx, cw, rgb_sum);
    k_final<<<(R*4 + 255)/256, 256, 0, stream>>>(rgb_sum, accb, depthb, (float*)d_out, R);
}

// Round 11
// 341.292 us; speedup vs baseline: 1.7207x; 1.7207x over previous
//
#include <hip/hip_runtime.h>

#define G 300
#define PIX (G*G)
#define CD 16
#define NS 512
#define STEP_F 0.005016722408026756f
#define C23 (2.0f/3.0f)

__device__ __forceinline__ float softplus_stable(float x){
    return (x > 0.f) ? (x + log1pf(expf(-x))) : log1pf(expf(x));
}

// Contraction barrier: pins x to a VGPR and "observes" it, so mul->add pairs
// across it CANNOT be fused into FMA. (HIP's __fmul_rn/__fadd_rn are NOT
// barriers — benched bit-identical with/without. This barrier is what made
// the bench PASS in R10. DO NOT REMOVE.)
__device__ __forceinline__ float nofuse(float x){
    asm("" : "+v"(x));
    return x;
}

// ---------------- transpose: [3][16][H][W] -> [3][H][W][16] ----------------
__global__ void k_tr_plane(const float* __restrict__ in, float* __restrict__ out){
    int pix = blockIdx.x * blockDim.x + threadIdx.x;
    if (pix >= 3*PIX) return;
    int p = pix / PIX;
    int rem = pix - p*PIX;
    float v[CD];
    #pragma unroll
    for (int c = 0; c < CD; ++c) v[c] = in[((size_t)(p*CD + c))*PIX + rem];
    float4* o4 = (float4*)(out + (size_t)pix*CD);
    #pragma unroll
    for (int q = 0; q < 4; ++q) o4[q] = make_float4(v[4*q+0], v[4*q+1], v[4*q+2], v[4*q+3]);
}

__global__ void k_tr_line(const float* __restrict__ in, float* __restrict__ out){
    int i = blockIdx.x * blockDim.x + threadIdx.x;
    if (i >= 3*G) return;
    int p = i / G;
    int z = i - p*G;
    float v[CD];
    #pragma unroll
    for (int c = 0; c < CD; ++c) v[c] = in[((size_t)(p*CD + c))*G + z];
    float4* o4 = (float4*)(out + (size_t)i*CD);
    #pragma unroll
    for (int q = 0; q < 4; ++q) o4[q] = make_float4(v[4*q+0], v[4*q+1], v[4*q+2], v[4*q+3]);
}

// f32 tmin chain: subs/divs/min/max only — no contractible mul+add pairs.
__device__ __forceinline__ float ray_tmin_f(float ox, float oy, float oz,
                                            float dx, float dy, float dz){
    const float vx = (dx == 0.f) ? 1e-6f : dx;
    const float vy = (dy == 0.f) ? 1e-6f : dy;
    const float vz = (dz == 0.f) ? 1e-6f : dz;
    const float ax = (1.5f - ox) / vx;
    const float bx = (-1.5f - ox) / vx;
    const float ay = (1.5f - oy) / vy;
    const float by = (-1.5f - oy) / vy;
    const float az = (1.5f - oz) / vz;
    const float bz = (-1.5f - oz) / vz;
    float t = fmaxf(fmaxf(fminf(ax,bx), fminf(ay,by)), fminf(az,bz));
    return fminf(fmaxf(t, 2.0f), 6.0f);
}

// ------- density: unfused-f32 decisions + float4 transposed taps + f64 parallel scan -------
// (FROZEN — this exact code passed correctness in R10.)
__global__ __launch_bounds__(512) void k_density(
    const float* __restrict__ rays,
    const float* __restrict__ tp, const float* __restrict__ tl,
    float* __restrict__ acc_out, float* __restrict__ depth_out,
    int* __restrict__ cnt, int* __restrict__ cidx, float* __restrict__ cw)
{
    __shared__ double s_wprod[8];
    __shared__ double s_acc[8];
    __shared__ double s_dep[8];
    __shared__ int    s_wbase[8];
    __shared__ int    s_gbase;

    const int r    = blockIdx.x;
    const int s    = threadIdx.x;
    const int lane = s & 63;
    const int wid  = s >> 6;

    const float oxf = rays[r*6+0], oyf = rays[r*6+1], ozf = rays[r*6+2];
    const float dxf = rays[r*6+3], dyf = rays[r*6+4], dzf = rays[r*6+5];

    const float tmin = ray_tmin_f(oxf, oyf, ozf, dxf, dyf, dzf);

    // numpy-exact UNFUSED: z = tmin + (STEP*s); p = o + (d*z)
    const float zv   = tmin + nofuse(STEP_F * (float)s);
    const float zv1  = tmin + nofuse(STEP_F * (float)(s+1));
    const float dist = (s == NS-1) ? 0.f : (zv1 - zv);

    const float px = oxf + nofuse(dxf * zv);
    const float py = oyf + nofuse(dyf * zv);
    const float pz = ozf + nofuse(dzf * zv);
    const bool valid = (px >= -1.5f) && (px <= 1.5f) && (py >= -1.5f) && (py <= 1.5f)
                    && (pz >= -1.5f) && (pz <= 1.5f);

    float alpha = 0.f;
    if (valid){
        const float xn = nofuse((px + 1.5f)*C23) - 1.f;
        const float yn = nofuse((py + 1.5f)*C23) - 1.f;
        const float zn = nofuse((pz + 1.5f)*C23) - 1.f;
        const float pu[3] = {xn, xn, yn};
        const float pv[3] = {yn, zn, zn};
        const float pl[3] = {zn, yn, xn};
        float feat = 0.f;
        #pragma unroll
        for (int pp = 0; pp < 3; ++pp){
            const float fx = (pu[pp] + 1.f) * 0.5f * (float)(G-1);
            const float fy = (pv[pp] + 1.f) * 0.5f * (float)(G-1);
            const float fz = (pl[pp] + 1.f) * 0.5f * (float)(G-1);
            const float x0f = floorf(fx), y0f = floorf(fy), z0f = floorf(fz);
            const float wx = fx - x0f, wy = fy - y0f, wz = fz - z0f;
            const int x0 = (int)x0f, y0 = (int)y0f, zq0 = (int)z0f;
            const int x1 = min(x0+1, G-1), y1 = min(y0+1, G-1), zq1 = min(zq0+1, G-1);
            const float wxe = (x0  + 1 < G) ? wx : 0.f;
            const float wye = (y0  + 1 < G) ? wy : 0.f;
            const float wze = (zq0 + 1 < G) ? wz : 0.f;
            const float w00 = (1.f-wx)*(1.f-wy);
            const float w01 = wxe*(1.f-wy);
            const float w10 = (1.f-wx)*wye;
            const float w11 = wxe*wye;
            const float u0 = 1.f - wz, u1 = wze;
            const float4* b00 = (const float4*)(tp + ((size_t)pp*PIX + y0*G + x0)*CD);
            const float4* b01 = (const float4*)(tp + ((size_t)pp*PIX + y0*G + x1)*CD);
            const float4* b10 = (const float4*)(tp + ((size_t)pp*PIX + y1*G + x0)*CD);
            const float4* b11 = (const float4*)(tp + ((size_t)pp*PIX + y1*G + x1)*CD);
            const float4* l0  = (const float4*)(tl + ((size_t)pp*G + zq0)*CD);
            const float4* l1  = (const float4*)(tl + ((size_t)pp*G + zq1)*CD);
            #pragma unroll
            for (int q = 0; q < 4; ++q){
                const float4 t00 = b00[q], t01 = b01[q], t10 = b10[q], t11 = b11[q];
                const float4 a0 = l0[q], a1 = l1[q];
                feat += (w00*t00.x + w01*t01.x + w10*t10.x + w11*t11.x) * (u0*a0.x + u1*a1.x);
                feat += (w00*t00.y + w01*t01.y + w10*t10.y + w11*t11.y) * (u0*a0.y + u1*a1.y);
                feat += (w00*t00.z + w01*t01.z + w10*t10.z + w11*t11.z) * (u0*a0.z + u1*a1.z);
                feat += (w00*t00.w + w01*t01.w + w10*t10.w + w11*t11.w) * (u0*a0.w + u1*a1.w);
            }
        }
        const float sigma = softplus_stable(feat - 10.0f);
        alpha = 1.f - expf(-(sigma * dist * 25.0f));
    }

    // f64 transmittance scan
    const double term = (1.0 - (double)alpha) + 1e-10;
    double v = term;
    #pragma unroll
    for (int off = 1; off < 64; off <<= 1){
        double u = __shfl_up(v, off, 64);
        if (lane >= off) v *= u;
    }
    double excl = __shfl_up(v, 1, 64);
    if (lane == 0) excl = 1.0;
    if (lane == 63) s_wprod[wid] = v;
    __syncthreads();
    if (s == 0){
        double p = 1.0;
        #pragma unroll
        for (int w = 0; w < 8; ++w){ double t = s_wprod[w]; s_wprod[w] = p; p *= t; }
    }
    __syncthreads();
    const double T = excl * s_wprod[wid];
    const double w = (double)alpha * T;

    double a_c = w;
    double d_c = w * (double)zv;
    #pragma unroll
    for (int off = 32; off > 0; off >>= 1){
        a_c += __shfl_down(a_c, off, 64);
        d_c += __shfl_down(d_c, off, 64);
    }
    if (lane == 0){ s_acc[wid] = a_c; s_dep[wid] = d_c; }

    const bool keep = w > 1e-4;
    const unsigned long long m = __ballot(keep);
    if (lane == 0) s_wbase[wid] = __popcll(m);
    __syncthreads();
    if (s == 0){
        double A = 0.0, D = 0.0;
        #pragma unroll
        for (int q = 0; q < 8; ++q){ A += s_acc[q]; D += s_dep[q]; }
        acc_out[r] = (float)A; depth_out[r] = (float)D;
        int tot = 0;
        #pragma unroll
        for (int q = 0; q < 8; ++q){ int c = s_wbase[q]; s_wbase[q] = tot; tot += c; }
        s_gbase = atomicAdd(cnt, tot);
    }
    __syncthreads();
    if (keep){
        const int off = s_gbase + s_wbase[wid] + (int)__popcll(m & ((1ull << lane) - 1ull));
        cidx[off] = (r << 9) | s;
        cw[off]   = (float)w;
    }
}

// ------------- color sampling + MLP on compacted points (v2: 4x4 tiles, H2 aliases X) -------------
__global__ __launch_bounds__(256) void k_color(
    const float* __restrict__ rays,
    const float* __restrict__ tp, const float* __restrict__ tl,
    const float* __restrict__ bw,
    const float* __restrict__ w1, const float* __restrict__ b1,
    const float* __restrict__ w2, const float* __restrict__ b2,
    const float* __restrict__ w3, const float* __restrict__ b3,
    const int* __restrict__ cnt, const int* __restrict__ cidx, const float* __restrict__ cw,
    float* __restrict__ rgb_sum)
{
    __shared__ float X [150][32];     // input features; rows 0..127 reused as H2 after GEMM2
    __shared__ float H1[128][32];     // also aliased as F[48][32] during color sampling
    __shared__ float xn_s[3][32];
    __shared__ int   pid[32];
    __shared__ float pw [32];
    float (*F)[32]  = (float(*)[32])H1;   // F dead before H1 written
    float (*H2)[32] = (float(*)[32])X;    // X dead after GEMM1 reads it

    const int t = threadIdx.x;
    const int p = t & 31;
    const int g = t >> 5;
    const int pq = t & 7;      // point-quad id: points 4*pq .. 4*pq+3
    const int p0 = pq << 2;
    const int jr = t >> 3;     // row base: rows jr + 32*v, v<4
    const int count   = *cnt;
    const int nchunks = (count + 31) >> 5;

    for (int ch = blockIdx.x; ch < nchunks; ch += gridDim.x){
        const int base = ch << 5;

        // ---- stage point coords / dirs ----
        if (t < 32){
            const int i  = base + t;
            const int id = (i < count) ? cidx[i] : -1;
            pid[t] = id;
            pw[t]  = (i < count) ? cw[i] : 0.f;
            float xn = 0.f, yn = 0.f, zn = 0.f, ddx = 0.f, ddy = 0.f, ddz = 0.f;
            if (id >= 0){
                const int r = id >> 9, sm = id & 511;
                const float oxf = rays[r*6+0], oyf = rays[r*6+1], ozf = rays[r*6+2];
                ddx = rays[r*6+3]; ddy = rays[r*6+4]; ddz = rays[r*6+5];
                const float tmin = ray_tmin_f(oxf, oyf, ozf, ddx, ddy, ddz);
                const float zv = tmin + nofuse(STEP_F * (float)sm);
                const float px = oxf + nofuse(ddx * zv);
                const float py = oyf + nofuse(ddy * zv);
                const float pz = ozf + nofuse(ddz * zv);
                xn = nofuse((px + 1.5f)*C23) - 1.f;
                yn = nofuse((py + 1.5f)*C23) - 1.f;
                zn = nofuse((pz + 1.5f)*C23) - 1.f;
            }
            xn_s[0][t] = xn; xn_s[1][t] = yn; xn_s[2][t] = zn;
            X[27][t] = ddx; X[28][t] = ddy; X[29][t] = ddz;
        }
        __syncthreads();

        // ---- color sampling: 2 channels per plane per thread-group ----
        {
            const int c0 = g*2;
            const bool live = pid[p] >= 0;
            const float xn = xn_s[0][p], yn = xn_s[1][p], zn = xn_s[2][p];
            const float pu[3] = {xn, xn, yn};
            const float pv[3] = {yn, zn, zn};
            const float pl[3] = {zn, yn, xn};
            #pragma unroll
            for (int pp = 0; pp < 3; ++pp){
                float f0 = 0.f, f1 = 0.f;
                if (live){
                    const float fx = (pu[pp] + 1.f) * 0.5f * (float)(G-1);
                    const float fy = (pv[pp] + 1.f) * 0.5f * (float)(G-1);
                    const float fz = (pl[pp] + 1.f) * 0.5f * (float)(G-1);
                    const float x0f = floorf(fx), y0f = floorf(fy), z0f = floorf(fz);
                    const float wx = fx - x0f, wy = fy - y0f, wz = fz - z0f;
                    const int x0 = (int)x0f, y0 = (int)y0f, zq0 = (int)z0f;
                    const int x1 = min(x0+1, G-1), y1 = min(y0+1, G-1), zq1 = min(zq0+1, G-1);
                    const float wxe = (x0  < G-1) ? wx : 0.f;
                    const float wye = (y0  < G-1) ? wy : 0.f;
                    const float wze = (zq0 < G-1) ? wz : 0.f;
                    const float w00 = (1.f-wx)*(1.f-wy);
                    const float w01 = wxe*(1.f-wy);
                    const float w10 = (1.f-wx)*wye;
                    const float w11 = wxe*wye;
                    const float u0 = 1.f - wz, u1 = wze;
                    const float* base00 = tp + ((size_t)pp*PIX + y0*G + x0)*CD + c0;
                    const float* base01 = tp + ((size_t)pp*PIX + y0*G + x1)*CD + c0;
                    const float* base10 = tp + ((size_t)pp*PIX + y1*G + x0)*CD + c0;
                    const float* base11 = tp + ((size_t)pp*PIX + y1*G + x1)*CD + c0;
                    const float* lb0    = tl + ((size_t)pp*G + zq0)*CD + c0;
                    const float* lb1    = tl + ((size_t)pp*G + zq1)*CD + c0;
                    const float2 t00 = *(const float2*)base00;
                    const float2 t01 = *(const float2*)base01;
                    const float2 t10 = *(const float2*)base10;
                    const float2 t11 = *(const float2*)base11;
                    const float2 a0  = *(const float2*)lb0;
                    const float2 a1  = *(const float2*)lb1;
                    f0 = (w00*t00.x + w01*t01.x + w10*t10.x + w11*t11.x) * (u0*a0.x + u1*a1.x);
                    f1 = (w00*t00.y + w01*t01.y + w10*t10.y + w11*t11.y) * (u0*a0.y + u1*a1.y);
                }
                F[pp*16 + c0    ][p] = f0;
                F[pp*16 + c0 + 1][p] = f1;
            }
        }
        __syncthreads();

        // ---- app_feat = basis_W (27x48) @ F ----
        {
            const int o0 = g, o1 = g + 8, o2 = g + 16;
            const int o3 = (g < 3) ? (g + 24) : 0;
            float a0 = 0.f, a1 = 0.f, a2 = 0.f, a3 = 0.f;
            for (int k = 0; k < 48; k += 4){
                const float x0 = F[k  ][p], x1 = F[k+1][p];
                const float x2 = F[k+2][p], x3 = F[k+3][p];
                const float4 v0 = *(const float4*)(bw + o0*48 + k);
                const float4 v1 = *(const float4*)(bw + o1*48 + k);
                const float4 v2 = *(const float4*)(bw + o2*48 + k);
                const float4 v3 = *(const float4*)(bw + o3*48 + k);
                a0 = fmaf(v0.x,x0,fmaf(v0.y,x1,fmaf(v0.z,x2,fmaf(v0.w,x3,a0))));
                a1 = fmaf(v1.x,x0,fmaf(v1.y,x1,fmaf(v1.z,x2,fmaf(v1.w,x3,a1))));
                a2 = fmaf(v2.x,x0,fmaf(v2.y,x1,fmaf(v2.z,x2,fmaf(v2.w,x3,a2))));
                a3 = fmaf(v3.x,x0,fmaf(v3.y,x1,fmaf(v3.z,x2,fmaf(v3.w,x3,a3))));
            }
            __syncthreads();
            X[o0][p] = a0; X[o1][p] = a1; X[o2][p] = a2;
            if (g < 3) X[g+24][p] = a3;
        }
        __syncthreads();

        // ---- positional encoding ----
        #pragma unroll
        for (int i = 0; i < 7; ++i){
            const int mf = g + 8*i;
            if (mf < 54){
                const int m = mf >> 1, f = mf & 1;
                const float a = X[m][p] * (f ? 2.f : 1.f);
                float sv, cv; sincosf(a, &sv, &cv);
                X[30+mf][p] = sv; X[84+mf][p] = cv;
            }
        }
        if (g < 6){
            const int j = g >> 1, f = g & 1;
            const float a = X[27+j][p] * (f ? 2.f : 1.f);
            float sv, cv; sincosf(a, &sv, &cv);
            X[138+g][p] = sv; X[144+g][p] = cv;
        }
        __syncthreads();

        // ---- GEMM1: H1 = relu(W1 @ X + b1); 4 rows x 4 points per thread ----
        {
            float acc[4][4];
            #pragma unroll
            for (int v = 0; v < 4; ++v){
                const float b = b1[jr + 32*v];
                acc[v][0] = b; acc[v][1] = b; acc[v][2] = b; acc[v][3] = b;
            }
            for (int k = 0; k < 150; k += 2){
                const float4 x0 = *(const float4*)&X[k  ][p0];
                const float4 x1 = *(const float4*)&X[k+1][p0];
                #pragma unroll
                for (int v = 0; v < 4; ++v){
                    const float2 w = *(const float2*)(w1 + (jr + 32*v)*150 + k);
                    acc[v][0] = fmaf(w.y, x1.x, fmaf(w.x, x0.x, acc[v][0]));
                    acc[v][1] = fmaf(w.y, x1.y, fmaf(w.x, x0.y, acc[v][1]));
                    acc[v][2] = fmaf(w.y, x1.z, fmaf(w.x, x0.z, acc[v][2]));
                    acc[v][3] = fmaf(w.y, x1.w, fmaf(w.x, x0.w, acc[v][3]));
                }
            }
            #pragma unroll
            for (int v = 0; v < 4; ++v){
                float4 h;
                h.x = fmaxf(acc[v][0], 0.f); h.y = fmaxf(acc[v][1], 0.f);
                h.z = fmaxf(acc[v][2], 0.f); h.w = fmaxf(acc[v][3], 0.f);
                *(float4*)&H1[jr + 32*v][p0] = h;
            }
        }
        __syncthreads();

        // ---- GEMM2: H2 = relu(W2 @ H1 + b2); 4 rows x 4 points; H2 aliases X ----
        {
            float acc[4][4];
            #pragma unroll
            for (int v = 0; v < 4; ++v){
                const float b = b2[jr + 32*v];
                acc[v][0] = b; acc[v][1] = b; acc[v][2] = b; acc[v][3] = b;
            }
            for (int k = 0; k < 128; k += 4){
                const float4 h0 = *(const float4*)&H1[k  ][p0];
                const float4 h1 = *(const float4*)&H1[k+1][p0];
                const float4 h2 = *(const float4*)&H1[k+2][p0];
                const float4 h3 = *(const float4*)&H1[k+3][p0];
                #pragma unroll
                for (int v = 0; v < 4; ++v){
                    const float4 w = *(const float4*)(w2 + (jr + 32*v)*128 + k);
                    acc[v][0] = fmaf(w.w,h3.x,fmaf(w.z,h2.x,fmaf(w.y,h1.x,fmaf(w.x,h0.x,acc[v][0]))));
                    acc[v][1] = fmaf(w.w,h3.y,fmaf(w.z,h2.y,fmaf(w.y,h1.y,fmaf(w.x,h0.y,acc[v][1]))));
                    acc[v][2] = fmaf(w.w,h3.z,fmaf(w.z,h2.z,fmaf(w.y,h1.z,fmaf(w.x,h0.z,acc[v][2]))));
                    acc[v][3] = fmaf(w.w,h3.w,fmaf(w.z,h2.w,fmaf(w.y,h1.w,fmaf(w.x,h0.w,acc[v][3]))));
                }
            }
            __syncthreads();   // all GEMM1/X reads done before overwriting X with H2
            #pragma unroll
            for (int v = 0; v < 4; ++v){
                float4 h;
                h.x = fmaxf(acc[v][0], 0.f); h.y = fmaxf(acc[v][1], 0.f);
                h.z = fmaxf(acc[v][2], 0.f); h.w = fmaxf(acc[v][3], 0.f);
                *(float4*)&H2[jr + 32*v][p0] = h;
            }
        }
        __syncthreads();

        // ---- GEMM3 + sigmoid + weighted accumulate ----
        if (t < 96){
            const int j = g;           // 0..2
            if (pid[p] >= 0){
                float acc = b3[j];
                for (int k = 0; k < 128; k += 4){
                    const float4 w = *(const float4*)(w3 + j*128 + k);
                    acc = fmaf(w.x, H2[k  ][p], acc);
                    acc = fmaf(w.y, H2[k+1][p], acc);
                    acc = fmaf(w.z, H2[k+2][p], acc);
                    acc = fmaf(w.w, H2[k+3][p], acc);
                }
                const float rgb = 1.f / (1.f + expf(-acc));
                atomicAdd(&rgb_sum[(pid[p] >> 9)*3 + j], pw[p]*rgb);
            }
        }
        __syncthreads();
    }
}

// ------------- finalize -------------
__global__ void k_final(const float* __restrict__ rgb_sum, const float* __restrict__ acc,
                        const float* __restrict__ depth, float* __restrict__ out, int R){
    const int i = blockIdx.x * blockDim.x + threadIdx.x;
    if (i < R*3){
        const int r = i / 3;
        const float v = rgb_sum[i] + (1.f - acc[r]);
        out[i] = fminf(fmaxf(v, 0.f), 1.f);
    } else if (i < R*4){
        const int r = i - R*3;
        out[R*3 + r] = depth[r];
    }
}

extern "C" void kernel_launch(void* const* d_in, const int* in_sizes, int n_in,
                              void* d_out, int out_size, void* d_ws, size_t ws_size,
                              hipStream_t stream)
{
    const float* rays        = (const float*)d_in[0];
    const float* dense_plane = (const float*)d_in[1];
    const float* dense_line  = (const float*)d_in[2];
    const float* color_plane = (const float*)d_in[3];
    const float* color_line  = (const float*)d_in[4];
    const float* bw          = (const float*)d_in[5];
    const float* w1          = (const float*)d_in[6];
    const float* b1          = (const float*)d_in[7];
    const float* w2          = (const float*)d_in[8];
    const float* b2          = (const float*)d_in[9];
    const float* w3          = (const float*)d_in[10];
    const float* b3          = (const float*)d_in[11];
    const int R = in_sizes[0] / 6;   // 2048

    char* ws = (char*)d_ws;
    const size_t OFF_RGB  = 0;
    const size_t OFF_CNT  = (size_t)R*3*sizeof(float);
    const size_t OFF_ACC  = OFF_CNT + 256;
    const size_t OFF_DEP  = OFF_ACC + (size_t)R*sizeof(float);
    const size_t OFF_CIDX = OFF_DEP + (size_t)R*sizeof(float);
    const size_t OFF_CW   = OFF_CIDX + (size_t)R*NS*sizeof(int);
    const size_t OFF_TD   = OFF_CW  + (size_t)R*NS*sizeof(float);
    const size_t OFF_TC   = OFF_TD  + (size_t)3*PIX*CD*sizeof(float);
    const size_t OFF_TDL  = OFF_TC  + (size_t)3*PIX*CD*sizeof(float);
    const size_t OFF_TCL  = OFF_TDL + (size_t)3*G*CD*sizeof(float);

    float* rgb_sum = (float*)(ws + OFF_RGB);
    int*   cnt     = (int*)  (ws + OFF_CNT);
    float* accb    = (float*)(ws + OFF_ACC);
    float* depthb  = (float*)(ws + OFF_DEP);
    int*   cidx    = (int*)  (ws + OFF_CIDX);
    float* cw      = (float*)(ws + OFF_CW);
    float* td      = (float*)(ws + OFF_TD);
    float* tc      = (float*)(ws + OFF_TC);
    float* tdl     = (float*)(ws + OFF_TDL);
    float* tcl     = (float*)(ws + OFF_TCL);

    hipMemsetAsync(ws, 0, OFF_CNT + sizeof(int), stream);

    const int pixb = (3*PIX + 255)/256;
    k_tr_plane<<<pixb, 256, 0, stream>>>(dense_plane, td);
    k_tr_plane<<<pixb, 256, 0, stream>>>(color_plane, tc);
    const int linb = (3*G + 255)/256;
    k_tr_line<<<linb, 256, 0, stream>>>(dense_line, tdl);
    k_tr_line<<<linb, 256, 0, stream>>>(color_line, tcl);

    k_density<<<R, 512, 0, stream>>>(rays, td, tdl, accb, depthb, cnt, cidx, cw);
    k_color<<<1024, 256, 0, stream>>>(rays, tc, tcl, bw, w1, b1, w2, b2, w3, b3,
                                      cnt, cidx, cw, rgb_sum);
    k_final<<<(R*4 + 255)/256, 256, 0, stream>>>(rgb_sum, accb, depthb, (float*)d_out, R);
}